// Round 9
// baseline (647.792 us; speedup 1.0000x reference)
//
#include <hip/hip_runtime.h>

#define H 64
#define NE 1500000
#define NLOC 20000
#define NEXP 200000
#define NL 400000
#define PAD_E 32
#define PAD_L 128
#define EPT 8
#define FILL_CHUNK 2048
#define NCHUNK ((NE + FILL_CHUNK - 1) / FILL_CHUNK)   // 733

// HW_REG_XCC_ID (id 20, gfx940+), offset 0, size 4 bits
#define XCC_GETREG_IMM ((20) | ((0) << 6) | ((4 - 1) << 11))

// ---- workspace layout (bytes) ----
// cnt_loc [0,80000)  cnt_exp [80000,880000)  qcur [880000,880064)
// nbr_loc [880064,11120064)  nbr_exp(u16) [11120064,23920064)
// Ylh(f16)  [23920064,26480064)   Y2fh(f16) [26480064,29040064)
// z_loc(f32)[29040064,34160064)   P(f32)    [34160064,39280064)
// ZE(f16)   [39280064,64880064)   z_exph -> Qh (in-place)
// TH(f16)   [64880064,90480064)   T1h -> T2'h
// Wf_q [90480064) Wf_y2 [90496448) Wf_t2 [90512832) Wf_p [90529216)
// bf_q [90545600) bf_p [90545856)
#define WS_NEED 90546112ULL

typedef int vint4 __attribute__((ext_vector_type(4)));
typedef _Float16 f16x8 __attribute__((ext_vector_type(8)));
typedef float f32x4 __attribute__((ext_vector_type(4)));

__device__ __forceinline__ float bcastf(float v, int k) {
  return __int_as_float(__builtin_amdgcn_readlane(__float_as_int(v), k));
}
__device__ __forceinline__ int bcasti(int v, int k) {
  return __builtin_amdgcn_readlane(v, k);
}
__device__ __forceinline__ int atomLocal(int* p, int v) {
  // workgroup scope on global mem -> no sc1 -> executes in the XCD-local L2.
  // Valid here because each partition's counters are touched by ONE XCD only
  // (blocks select partition = their measured XCC_ID).
  return __hip_atomic_fetch_add(p, v, __ATOMIC_RELAXED, __HIP_MEMORY_SCOPE_WORKGROUP);
}

// XCD-bound CSR build: block reads its TRUE XCD id, drains per-XCD chunk
// queue; all cursor atomics + nbr stores for its partition stay in the local
// L2 (no fabric RMW). Queue grabs use agent scope (6K ops total, cheap).
__global__ __launch_bounds__(256) void fill_kernel(
    const int* __restrict__ src, const int* __restrict__ dst,
    int* __restrict__ cnt_loc, int* __restrict__ cnt_exp,
    int* __restrict__ nbr_loc, unsigned short* __restrict__ nbr_exp,
    int* __restrict__ qcur)
{
  const int p = __builtin_amdgcn_s_getreg(XCC_GETREG_IMM) & 7;
  const int elo = p * (NEXP / 8), ehi = elo + NEXP / 8;
  const int llo = p * (NLOC / 8), lhi = llo + NLOC / 8;
  __shared__ int chunk_s;
  for (;;) {
    __syncthreads();
    if (threadIdx.x == 0) chunk_s = atomicAdd(&qcur[p], 1);
    __syncthreads();
    const int chunk = chunk_s;
    if (chunk >= NCHUNK) return;
    const long base = (long)chunk * FILL_CHUNK + threadIdx.x * EPT;
    if (base >= NE) continue;
    vint4 s0 = __builtin_nontemporal_load((const vint4*)(src + base));
    vint4 s1 = __builtin_nontemporal_load((const vint4*)(src + base + 4));
    vint4 d0 = __builtin_nontemporal_load((const vint4*)(dst + base));
    vint4 d1 = __builtin_nontemporal_load((const vint4*)(dst + base + 4));
    int ss[EPT] = {s0.x, s0.y, s0.z, s0.w, s1.x, s1.y, s1.z, s1.w};
    int dd[EPT] = {d0.x, d0.y, d0.z, d0.w, d1.x, d1.y, d1.z, d1.w};
#pragma unroll
    for (int k = 0; k < EPT; k++) {
      const int d = dd[k];
      if (d >= elo && d < ehi) {
        int pos = atomLocal(&cnt_exp[d], 1);
        if (pos < PAD_E) nbr_exp[d * PAD_E + pos] = (unsigned short)ss[k];
      }
    }
#pragma unroll
    for (int k = 0; k < EPT; k++) {
      const int s = ss[k];
      if (s >= llo && s < lhi) {
        int pos = atomLocal(&cnt_loc[s], 1);
        if (pos < PAD_L) nbr_loc[s * PAD_L + pos] = dd[k];
      }
    }
  }
}

// Fold layer-2 weights through the decoder (valid: no relu on layer 2).
// Blocks 0-3: C = A @ B (64x64 each). Block 4: bias folds.
__global__ __launch_bounds__(256) void fold_kernel(
    const float* __restrict__ W2r_of, const float* __restrict__ W2l_of,
    const float* __restrict__ W2l_rev, const float* __restrict__ W2r_rev,
    const float* __restrict__ dW1, const float* __restrict__ b2_of,
    const float* __restrict__ b2_rev,
    float* __restrict__ Wf_q, float* __restrict__ Wf_y2,
    float* __restrict__ Wf_t2, float* __restrict__ Wf_p,
    float* __restrict__ bf_q, float* __restrict__ bf_p)
{
  const int lane = threadIdx.x & 63;
  const int w = threadIdx.x >> 6;
  const float* dW1a = dW1;
  const float* dW1b = dW1 + H * H;
  if (blockIdx.x < 4) {
    const float* A; const float* B; float* C;
    switch (blockIdx.x) {
      case 0:  A = W2r_of;  B = dW1b; C = Wf_q;  break;
      case 1:  A = W2l_of;  B = dW1b; C = Wf_y2; break;
      case 2:  A = W2l_rev; B = dW1a; C = Wf_t2; break;
      default: A = W2r_rev; B = dW1a; C = Wf_p;  break;
    }
    float b[H];
#pragma unroll
    for (int k = 0; k < H; k++) b[k] = B[k * H + lane];
    for (int r = w * 16; r < w * 16 + 16; r++) {
      const float xv = A[r * H + lane];
      float a0 = 0.f, a1 = 0.f;
#pragma unroll
      for (int k = 0; k < H; k += 2) {
        a0 += bcastf(xv, k)     * b[k];
        a1 += bcastf(xv, k + 1) * b[k + 1];
      }
      C[r * H + lane] = a0 + a1;
    }
  } else if (w < 2) {
    const float* bv_src = (w == 0) ? b2_of : b2_rev;
    const float* B      = (w == 0) ? dW1b  : dW1a;
    float* o            = (w == 0) ? bf_q  : bf_p;
    float wk[H];
#pragma unroll
    for (int k = 0; k < H; k++) wk[k] = B[k * H + lane];
    const float bv = bv_src[lane];
    float a = 0.f;
#pragma unroll
    for (int k = 0; k < H; k++) a += bcastf(bv, k) * wk[k];
    o[lane] = a;
  }
}

// out16 = x @ W (no bias); fp32 in, fp16 out. 20K rows.
__global__ __launch_bounds__(256, 4) void dense_linear_kernel(
    const float* __restrict__ x, _Float16* __restrict__ out16,
    const float* __restrict__ W, int n)
{
  const int lane = threadIdx.x & 63;
  const int gw = (blockIdx.x * 256 + threadIdx.x) >> 6;
  const int nw = (gridDim.x * 256) >> 6;
  float w[H];
#pragma unroll
  for (int k = 0; k < H; k++) w[k] = W[k * H + lane];
  for (int i = gw; i < n; i += nw) {
    const float xv = x[i * H + lane];
    float a0 = 0.f, a1 = 0.f;
#pragma unroll
    for (int k = 0; k < H; k += 2) {
      a0 += bcastf(xv, k)     * w[k];
      a1 += bcastf(xv, k + 1) * w[k + 1];
    }
    out16[i * H + lane] = (_Float16)(a0 + a1);
  }
}

// Exp-side MFMA pass (dual-B, optional gather/bias/relu). Block = 16 rows.
__global__ __launch_bounds__(256, 4) void mfma_pass_kernel(
    const unsigned short* __restrict__ nbr, const int* __restrict__ cnt,
    const _Float16* __restrict__ y,
    const float* a32, const _Float16* a16,
    _Float16* out1, const float* __restrict__ W1,
    const float* __restrict__ bias, int relu,
    _Float16* out2, const float* __restrict__ W2)
{
  const int w = threadIdx.x >> 6;
  const int lane = threadIdx.x & 63;
  const int q = lane >> 4;
  const int cidx = lane & 15;
  const int rb = blockIdx.x * 16;

  __shared__ float Gs[16 * H];

  f16x8 b1lo, b1hi, b2lo, b2hi;
#pragma unroll
  for (int j = 0; j < 8; j++) {
    b1lo[j] = (_Float16)W1[(q * 8 + j) * H + w * 16 + cidx];
    b1hi[j] = (_Float16)W1[(32 + q * 8 + j) * H + w * 16 + cidx];
  }
  if (out2) {
#pragma unroll
    for (int j = 0; j < 8; j++) {
      b2lo[j] = (_Float16)W2[(q * 8 + j) * H + w * 16 + cidx];
      b2hi[j] = (_Float16)W2[(32 + q * 8 + j) * H + w * 16 + cidx];
    }
  }

  if (y) {
    for (int rr = 0; rr < 4; rr++) {
      const int i = rb + w * 4 + rr;
      const int c = cnt[i];
      const int cc = min(c, PAD_E);
      const unsigned short* nb = nbr + (long)i * PAD_E;
      float s0 = 0.f, s1 = 0.f, s2 = 0.f, s3 = 0.f;
      const int id = (lane < cc) ? (int)nb[lane] : 0;
      int k = 0;
      const int m4 = cc & ~3;
      for (; k < m4; k += 4) {
        const int i0 = bcasti(id, k), i1 = bcasti(id, k + 1),
                  i2 = bcasti(id, k + 2), i3 = bcasti(id, k + 3);
        s0 += (float)y[(long)i0 * H + lane];
        s1 += (float)y[(long)i1 * H + lane];
        s2 += (float)y[(long)i2 * H + lane];
        s3 += (float)y[(long)i3 * H + lane];
      }
      for (; k < cc; k++) s0 += (float)y[(long)bcasti(id, k) * H + lane];
      Gs[(w * 4 + rr) * H + lane] =
          ((s0 + s1) + (s2 + s3)) / fmaxf((float)c, 1.0f);
    }
  }

  f16x8 a0, a1;
  if (a16) {
    const _Float16* ar = a16 + (long)(rb + cidx) * H;
    a0 = *(const f16x8*)(ar + q * 8);
    a1 = *(const f16x8*)(ar + 32 + q * 8);
  } else {
    const float* ar = a32 + (long)(rb + cidx) * H;
#pragma unroll
    for (int j = 0; j < 8; j++) {
      a0[j] = (_Float16)ar[q * 8 + j];
      a1[j] = (_Float16)ar[32 + q * 8 + j];
    }
  }
  f32x4 acc1 = {0.f, 0.f, 0.f, 0.f};
  acc1 = __builtin_amdgcn_mfma_f32_16x16x32_f16(a0, b1lo, acc1, 0, 0, 0);
  acc1 = __builtin_amdgcn_mfma_f32_16x16x32_f16(a1, b1hi, acc1, 0, 0, 0);
  f32x4 acc2 = {0.f, 0.f, 0.f, 0.f};
  if (out2) {
    acc2 = __builtin_amdgcn_mfma_f32_16x16x32_f16(a0, b2lo, acc2, 0, 0, 0);
    acc2 = __builtin_amdgcn_mfma_f32_16x16x32_f16(a1, b2hi, acc2, 0, 0, 0);
  }

  const float bj = bias ? bias[w * 16 + cidx] : 0.f;
  __syncthreads();   // Gs ready; all A loads drained before in-place stores
#pragma unroll
  for (int reg = 0; reg < 4; reg++) {
    const int r = q * 4 + reg;
    float v = acc1[reg] + bj;
    if (y) v += Gs[r * H + w * 16 + cidx];
    if (relu) v = fmaxf(v, 0.f);
    out1[(long)(rb + r) * H + w * 16 + cidx] = (_Float16)v;
    if (out2)
      out2[(long)(rb + r) * H + w * 16 + cidx] = (_Float16)acc2[reg];
  }
}

// Loc side: out = mean-gather(fp16 T rows) + x @ Wr + bias (opt relu), f32 out
__global__ __launch_bounds__(256, 4) void loc_gather_kernel(
    const int* __restrict__ nbr, const int* __restrict__ cnt,
    const _Float16* __restrict__ T, const float* __restrict__ x,
    float* __restrict__ out, const float* __restrict__ Wr,
    const float* __restrict__ bias, int n, int relu)
{
  const int lane = threadIdx.x & 63;
  const int gw = (blockIdx.x * 256 + threadIdx.x) >> 6;
  const int nw = (gridDim.x * 256) >> 6;
  float wr[H];
#pragma unroll
  for (int k = 0; k < H; k++) wr[k] = Wr[k * H + lane];
  const float bj = bias[lane];
  for (int i = gw; i < n; i += nw) {
    const int c = cnt[i];
    const int cc = min(c, PAD_L);
    const int* nb = nbr + (long)i * PAD_L;
    float s0 = 0.f, s1 = 0.f, s2 = 0.f, s3 = 0.f;
    int e = 0;
    while (e < cc) {
      const int m = min(cc - e, 64);
      const int id = (lane < m) ? nb[e + lane] : 0;
      int k = 0;
      const int m4 = m & ~3;
      for (; k < m4; k += 4) {
        const int i0 = bcasti(id, k), i1 = bcasti(id, k + 1),
                  i2 = bcasti(id, k + 2), i3 = bcasti(id, k + 3);
        s0 += (float)T[(long)i0 * H + lane];
        s1 += (float)T[(long)i1 * H + lane];
        s2 += (float)T[(long)i2 * H + lane];
        s3 += (float)T[(long)i3 * H + lane];
      }
      for (; k < m; k++) s0 += (float)T[(long)bcasti(id, k) * H + lane];
      e += m;
    }
    const float agg = ((s0 + s1) + (s2 + s3)) / fmaxf((float)c, 1.0f);
    const float xv = x[i * H + lane];
    float a0 = 0.f, a1 = 0.f;
#pragma unroll
    for (int k = 0; k < H; k += 2) {
      a0 += bcastf(xv, k)     * wr[k];
      a1 += bcastf(xv, k + 1) * wr[k + 1];
    }
    float acc = agg + bj + a0 + a1;
    if (relu) acc = fmaxf(acc, 0.0f);
    out[i * H + lane] = acc;
  }
}

// out[e] = sum_j relu(P[r,j] + Q[c,j] + db1[j]) * dW2[j] + db2
__global__ __launch_bounds__(256, 4) void edge_kernel(
    const int* __restrict__ row, const int* __restrict__ col,
    const float* __restrict__ P, const _Float16* __restrict__ Q,
    const float* __restrict__ db1, const float* __restrict__ dW2,
    const float* __restrict__ db2, float* __restrict__ out)
{
  const int lane = threadIdx.x & 63;
  const int gw = (blockIdx.x * 256 + threadIdx.x) >> 6;
  const int nw = (gridDim.x * 256) >> 6;
  const float bj = db1[lane];
  const float w2 = dW2[lane];
  const float b2 = db2[0];
  for (int e = gw * 2; e < NL; e += nw * 2) {
    const int r0 = row[e],     c0 = col[e];
    const int r1 = row[e + 1], c1 = col[e + 1];
    const float p0 = P[(long)r0 * H + lane];
    const float q0 = (float)Q[(long)c0 * H + lane];
    const float p1 = P[(long)r1 * H + lane];
    const float q1 = (float)Q[(long)c1 * H + lane];
    float h0 = fmaxf(p0 + q0 + bj, 0.0f) * w2;
    float h1 = fmaxf(p1 + q1 + bj, 0.0f) * w2;
#pragma unroll
    for (int off = 1; off < 64; off <<= 1) {
      h0 += __shfl_xor(h0, off);
      h1 += __shfl_xor(h1, off);
    }
    if (lane == 0) {
      out[e]     = h0 + b2;
      out[e + 1] = h1 + b2;
    }
  }
}

extern "C" void kernel_launch(void* const* d_in, const int* in_sizes, int n_in,
                              void* d_out, int out_size, void* d_ws, size_t ws_size,
                              hipStream_t stream) {
  const float* emb_loc = (const float*)d_in[0];
  const float* emb_exp = (const float*)d_in[1];
  const float* W1l_of  = (const float*)d_in[2];
  const float* b1_of   = (const float*)d_in[3];
  const float* W1r_of  = (const float*)d_in[4];
  const float* W1l_rev = (const float*)d_in[5];
  const float* b1_rev  = (const float*)d_in[6];
  const float* W1r_rev = (const float*)d_in[7];
  const float* W2l_of  = (const float*)d_in[8];
  const float* b2_of   = (const float*)d_in[9];
  const float* W2r_of  = (const float*)d_in[10];
  const float* W2l_rev = (const float*)d_in[11];
  const float* b2_rev  = (const float*)d_in[12];
  const float* W2r_rev = (const float*)d_in[13];
  const float* dW1     = (const float*)d_in[14];
  const float* db1     = (const float*)d_in[15];
  const float* dW2     = (const float*)d_in[16];
  const float* db2     = (const float*)d_in[17];
  const int*   edge_of = (const int*)d_in[18];
  const int*   eli     = (const int*)d_in[20];

  const int* src = edge_of;
  const int* dst = edge_of + NE;
  const int* row = eli;
  const int* col = eli + NL;

  if (ws_size < WS_NEED) return;

  char* ws = (char*)d_ws;
  int*            cnt_loc = (int*)(ws);
  int*            cnt_exp = (int*)(ws + 80000);
  int*            qcur    = (int*)(ws + 880000);
  int*            nbr_loc = (int*)(ws + 880064);
  unsigned short* nbr_exp = (unsigned short*)(ws + 11120064);
  _Float16*       Ylh     = (_Float16*)(ws + 23920064);
  _Float16*       Y2fh    = (_Float16*)(ws + 26480064);
  float*          z_loc   = (float*)(ws + 29040064);
  float*          P       = (float*)(ws + 34160064);
  _Float16*       ZE      = (_Float16*)(ws + 39280064);
  _Float16*       TH      = (_Float16*)(ws + 64880064);
  float*          Wf_q    = (float*)(ws + 90480064);
  float*          Wf_y2   = (float*)(ws + 90496448);
  float*          Wf_t2   = (float*)(ws + 90512832);
  float*          Wf_p    = (float*)(ws + 90529216);
  float*          bf_q    = (float*)(ws + 90545600);
  float*          bf_p    = (float*)(ws + 90545856);
  float*          out     = (float*)d_out;

  (void)hipMemsetAsync(ws, 0, 880064, stream);
  fill_kernel<<<2048, 256, 0, stream>>>(src, dst, cnt_loc, cnt_exp,
                                        nbr_loc, nbr_exp, qcur);
  fold_kernel<<<5, 256, 0, stream>>>(W2r_of, W2l_of, W2l_rev, W2r_rev,
                                     dW1, b2_of, b2_rev,
                                     Wf_q, Wf_y2, Wf_t2, Wf_p, bf_q, bf_p);

  // ---- layer 1 ----
  dense_linear_kernel<<<1280, 256, 0, stream>>>(emb_loc, Ylh, W1l_of, NLOC);
  // passA: z_exph = relu(emb_exp@W1r_of + gatherE(Ylh) + b1_of); T1h = emb_exp@W1l_rev
  mfma_pass_kernel<<<NEXP / 16, 256, 0, stream>>>(nbr_exp, cnt_exp, Ylh,
      emb_exp, (const _Float16*)nullptr, ZE, W1r_of, b1_of, 1, TH, W1l_rev);
  loc_gather_kernel<<<1250, 256, 0, stream>>>(nbr_loc, cnt_loc, TH,
      emb_loc, z_loc, W1r_rev, b1_rev, NLOC, 1);

  // ---- layer 2 + decoder transforms (folded: no relu on layer 2) ----
  dense_linear_kernel<<<1280, 256, 0, stream>>>(z_loc, Y2fh, Wf_y2, NLOC);
  // passB: Qh = z_exph@Wf_q + gatherE(Y2fh) + bf_q (in-place over ZE);
  //        T2'h = z_exph@Wf_t2 (over TH; T1h consumed)
  mfma_pass_kernel<<<NEXP / 16, 256, 0, stream>>>(nbr_exp, cnt_exp, Y2fh,
      (const float*)nullptr, ZE, ZE, Wf_q, bf_q, 0, TH, Wf_t2);
  // P = gatherL(T2'h) + z_loc@Wf_p + bf_p   (decoder-left, folded)
  loc_gather_kernel<<<1250, 256, 0, stream>>>(nbr_loc, cnt_loc, TH,
      z_loc, P, Wf_p, bf_p, NLOC, 0);

  // ---- decoder edge pass ----
  edge_kernel<<<2048, 256, 0, stream>>>(row, col, P, ZE,
                                        db1, dW2, db2, out);
}

// Round 10
// 600.213 us; speedup vs baseline: 1.0793x; 1.0793x over previous
//
#include <hip/hip_runtime.h>

#define H 64
#define NE 1500000
#define NLOC 20000
#define NEXP 200000
#define NL 400000
#define PAD_E 32
#define PAD_L 128
#define EPT 8
#define FILL_CHUNK 2048
#define NCHUNK ((NE + FILL_CHUNK - 1) / FILL_CHUNK)   // 733

// ---- workspace layout (bytes) ----
// cnt_loc [0,80000)  cnt_exp [80000,880000)
// nbr_loc [880064,11120064)  nbr_exp(u16) [11120064,23920064)
// Ylh(f16)  [23920064,26480064)   Y2fh(f16) [26480064,29040064)
// z_loc(f32)[29040064,34160064)   PH(f16)   [34160064,36720064)
// ZE(f16)   [39280064,64880064)   z_exph -> Qh (in-place)
// TH(f16)   [64880064,90480064)   T1h -> T2'h
// Wf_q [90480064) Wf_y2 [90496448) Wf_t2 [90512832) Wf_p [90529216)
// bf_q [90545600) bf_p [90545856)
#define WS_NEED 90546112ULL

typedef int vint4 __attribute__((ext_vector_type(4)));
typedef _Float16 f16x8 __attribute__((ext_vector_type(8)));
typedef float f32x4 __attribute__((ext_vector_type(4)));

__device__ __forceinline__ float bcastf(float v, int k) {
  return __int_as_float(__builtin_amdgcn_readlane(__float_as_int(v), k));
}
__device__ __forceinline__ int bcasti(int v, int k) {
  return __builtin_amdgcn_readlane(v, k);
}

// CSR build, r8-proven static structure (135us): partition = blockIdx&7
// (heuristic XCD affinity; correctness independent — agent-scope atomics),
// chunk = blockIdx>>3. NEW vs r8: non-temporal edge loads so the 24MB/XCD
// edge stream is marked evict-first and doesn't flush partially-filled nbr
// lines out of L2 before their sibling stores merge.
__global__ __launch_bounds__(256) void fill_kernel(
    const int* __restrict__ src, const int* __restrict__ dst,
    int* __restrict__ cnt_loc, int* __restrict__ cnt_exp,
    int* __restrict__ nbr_loc, unsigned short* __restrict__ nbr_exp)
{
  const int p = blockIdx.x & 7;
  const int chunk = blockIdx.x >> 3;
  const long base = (long)chunk * FILL_CHUNK + threadIdx.x * EPT;
  if (base >= NE) return;
  vint4 s0 = __builtin_nontemporal_load((const vint4*)(src + base));
  vint4 s1 = __builtin_nontemporal_load((const vint4*)(src + base + 4));
  vint4 d0 = __builtin_nontemporal_load((const vint4*)(dst + base));
  vint4 d1 = __builtin_nontemporal_load((const vint4*)(dst + base + 4));
  int ss[EPT] = {s0.x, s0.y, s0.z, s0.w, s1.x, s1.y, s1.z, s1.w};
  int dd[EPT] = {d0.x, d0.y, d0.z, d0.w, d1.x, d1.y, d1.z, d1.w};
  const int elo = p * (NEXP / 8), ehi = elo + NEXP / 8;
  const int llo = p * (NLOC / 8), lhi = llo + NLOC / 8;
#pragma unroll
  for (int k = 0; k < EPT; k++) {
    const int d = dd[k];
    if (d >= elo && d < ehi) {
      int pos = atomicAdd(&cnt_exp[d], 1);
      if (pos < PAD_E) nbr_exp[d * PAD_E + pos] = (unsigned short)ss[k];
    }
  }
#pragma unroll
  for (int k = 0; k < EPT; k++) {
    const int s = ss[k];
    if (s >= llo && s < lhi) {
      int pos = atomicAdd(&cnt_loc[s], 1);
      if (pos < PAD_L) nbr_loc[s * PAD_L + pos] = dd[k];
    }
  }
}

// Fold layer-2 weights through the decoder (valid: no relu on layer 2).
__global__ __launch_bounds__(256) void fold_kernel(
    const float* __restrict__ W2r_of, const float* __restrict__ W2l_of,
    const float* __restrict__ W2l_rev, const float* __restrict__ W2r_rev,
    const float* __restrict__ dW1, const float* __restrict__ b2_of,
    const float* __restrict__ b2_rev,
    float* __restrict__ Wf_q, float* __restrict__ Wf_y2,
    float* __restrict__ Wf_t2, float* __restrict__ Wf_p,
    float* __restrict__ bf_q, float* __restrict__ bf_p)
{
  const int lane = threadIdx.x & 63;
  const int w = threadIdx.x >> 6;
  const float* dW1a = dW1;
  const float* dW1b = dW1 + H * H;
  if (blockIdx.x < 4) {
    const float* A; const float* B; float* C;
    switch (blockIdx.x) {
      case 0:  A = W2r_of;  B = dW1b; C = Wf_q;  break;
      case 1:  A = W2l_of;  B = dW1b; C = Wf_y2; break;
      case 2:  A = W2l_rev; B = dW1a; C = Wf_t2; break;
      default: A = W2r_rev; B = dW1a; C = Wf_p;  break;
    }
    float b[H];
#pragma unroll
    for (int k = 0; k < H; k++) b[k] = B[k * H + lane];
    for (int r = w * 16; r < w * 16 + 16; r++) {
      const float xv = A[r * H + lane];
      float a0 = 0.f, a1 = 0.f;
#pragma unroll
      for (int k = 0; k < H; k += 2) {
        a0 += bcastf(xv, k)     * b[k];
        a1 += bcastf(xv, k + 1) * b[k + 1];
      }
      C[r * H + lane] = a0 + a1;
    }
  } else if (w < 2) {
    const float* bv_src = (w == 0) ? b2_of : b2_rev;
    const float* B      = (w == 0) ? dW1b  : dW1a;
    float* o            = (w == 0) ? bf_q  : bf_p;
    float wk[H];
#pragma unroll
    for (int k = 0; k < H; k++) wk[k] = B[k * H + lane];
    const float bv = bv_src[lane];
    float a = 0.f;
#pragma unroll
    for (int k = 0; k < H; k++) a += bcastf(bv, k) * wk[k];
    o[lane] = a;
  }
}

// out16 = x @ W (no bias); fp32 in, fp16 out. 20K rows.
__global__ __launch_bounds__(256, 4) void dense_linear_kernel(
    const float* __restrict__ x, _Float16* __restrict__ out16,
    const float* __restrict__ W, int n)
{
  const int lane = threadIdx.x & 63;
  const int gw = (blockIdx.x * 256 + threadIdx.x) >> 6;
  const int nw = (gridDim.x * 256) >> 6;
  float w[H];
#pragma unroll
  for (int k = 0; k < H; k++) w[k] = W[k * H + lane];
  for (int i = gw; i < n; i += nw) {
    const float xv = x[i * H + lane];
    float a0 = 0.f, a1 = 0.f;
#pragma unroll
    for (int k = 0; k < H; k += 2) {
      a0 += bcastf(xv, k)     * w[k];
      a1 += bcastf(xv, k + 1) * w[k + 1];
    }
    out16[i * H + lane] = (_Float16)(a0 + a1);
  }
}

// Exp-side MFMA pass (dual-B, optional gather/bias/relu). Block = 16 rows.
__global__ __launch_bounds__(256, 4) void mfma_pass_kernel(
    const unsigned short* __restrict__ nbr, const int* __restrict__ cnt,
    const _Float16* __restrict__ y,
    const float* a32, const _Float16* a16,
    _Float16* out1, const float* __restrict__ W1,
    const float* __restrict__ bias, int relu,
    _Float16* out2, const float* __restrict__ W2)
{
  const int w = threadIdx.x >> 6;
  const int lane = threadIdx.x & 63;
  const int q = lane >> 4;
  const int cidx = lane & 15;
  const int rb = blockIdx.x * 16;

  __shared__ float Gs[16 * H];

  f16x8 b1lo, b1hi, b2lo, b2hi;
#pragma unroll
  for (int j = 0; j < 8; j++) {
    b1lo[j] = (_Float16)W1[(q * 8 + j) * H + w * 16 + cidx];
    b1hi[j] = (_Float16)W1[(32 + q * 8 + j) * H + w * 16 + cidx];
  }
  if (out2) {
#pragma unroll
    for (int j = 0; j < 8; j++) {
      b2lo[j] = (_Float16)W2[(q * 8 + j) * H + w * 16 + cidx];
      b2hi[j] = (_Float16)W2[(32 + q * 8 + j) * H + w * 16 + cidx];
    }
  }

  if (y) {
    for (int rr = 0; rr < 4; rr++) {
      const int i = rb + w * 4 + rr;
      const int c = cnt[i];
      const int cc = min(c, PAD_E);
      const unsigned short* nb = nbr + (long)i * PAD_E;
      float s0 = 0.f, s1 = 0.f, s2 = 0.f, s3 = 0.f;
      const int id = (lane < cc) ? (int)nb[lane] : 0;
      int k = 0;
      const int m4 = cc & ~3;
      for (; k < m4; k += 4) {
        const int i0 = bcasti(id, k), i1 = bcasti(id, k + 1),
                  i2 = bcasti(id, k + 2), i3 = bcasti(id, k + 3);
        s0 += (float)y[(long)i0 * H + lane];
        s1 += (float)y[(long)i1 * H + lane];
        s2 += (float)y[(long)i2 * H + lane];
        s3 += (float)y[(long)i3 * H + lane];
      }
      for (; k < cc; k++) s0 += (float)y[(long)bcasti(id, k) * H + lane];
      Gs[(w * 4 + rr) * H + lane] =
          ((s0 + s1) + (s2 + s3)) / fmaxf((float)c, 1.0f);
    }
  }

  f16x8 a0, a1;
  if (a16) {
    const _Float16* ar = a16 + (long)(rb + cidx) * H;
    a0 = *(const f16x8*)(ar + q * 8);
    a1 = *(const f16x8*)(ar + 32 + q * 8);
  } else {
    const float* ar = a32 + (long)(rb + cidx) * H;
#pragma unroll
    for (int j = 0; j < 8; j++) {
      a0[j] = (_Float16)ar[q * 8 + j];
      a1[j] = (_Float16)ar[32 + q * 8 + j];
    }
  }
  f32x4 acc1 = {0.f, 0.f, 0.f, 0.f};
  acc1 = __builtin_amdgcn_mfma_f32_16x16x32_f16(a0, b1lo, acc1, 0, 0, 0);
  acc1 = __builtin_amdgcn_mfma_f32_16x16x32_f16(a1, b1hi, acc1, 0, 0, 0);
  f32x4 acc2 = {0.f, 0.f, 0.f, 0.f};
  if (out2) {
    acc2 = __builtin_amdgcn_mfma_f32_16x16x32_f16(a0, b2lo, acc2, 0, 0, 0);
    acc2 = __builtin_amdgcn_mfma_f32_16x16x32_f16(a1, b2hi, acc2, 0, 0, 0);
  }

  const float bj = bias ? bias[w * 16 + cidx] : 0.f;
  __syncthreads();   // Gs ready; all A loads drained before in-place stores
#pragma unroll
  for (int reg = 0; reg < 4; reg++) {
    const int r = q * 4 + reg;
    float v = acc1[reg] + bj;
    if (y) v += Gs[r * H + w * 16 + cidx];
    if (relu) v = fmaxf(v, 0.f);
    out1[(long)(rb + r) * H + w * 16 + cidx] = (_Float16)v;
    if (out2)
      out2[(long)(rb + r) * H + w * 16 + cidx] = (_Float16)acc2[reg];
  }
}

// Loc side: out = mean-gather(fp16 T rows) + x @ Wr + bias (opt relu).
// Output to f32 (out32) or f16 (out16), one of them null.
__global__ __launch_bounds__(256, 4) void loc_gather_kernel(
    const int* __restrict__ nbr, const int* __restrict__ cnt,
    const _Float16* __restrict__ T, const float* __restrict__ x,
    float* __restrict__ out32, _Float16* __restrict__ out16,
    const float* __restrict__ Wr, const float* __restrict__ bias,
    int n, int relu)
{
  const int lane = threadIdx.x & 63;
  const int gw = (blockIdx.x * 256 + threadIdx.x) >> 6;
  const int nw = (gridDim.x * 256) >> 6;
  float wr[H];
#pragma unroll
  for (int k = 0; k < H; k++) wr[k] = Wr[k * H + lane];
  const float bj = bias[lane];
  for (int i = gw; i < n; i += nw) {
    const int c = cnt[i];
    const int cc = min(c, PAD_L);
    const int* nb = nbr + (long)i * PAD_L;
    float s0 = 0.f, s1 = 0.f, s2 = 0.f, s3 = 0.f;
    int e = 0;
    while (e < cc) {
      const int m = min(cc - e, 64);
      const int id = (lane < m) ? nb[e + lane] : 0;
      int k = 0;
      const int m4 = m & ~3;
      for (; k < m4; k += 4) {
        const int i0 = bcasti(id, k), i1 = bcasti(id, k + 1),
                  i2 = bcasti(id, k + 2), i3 = bcasti(id, k + 3);
        s0 += (float)T[(long)i0 * H + lane];
        s1 += (float)T[(long)i1 * H + lane];
        s2 += (float)T[(long)i2 * H + lane];
        s3 += (float)T[(long)i3 * H + lane];
      }
      for (; k < m; k++) s0 += (float)T[(long)bcasti(id, k) * H + lane];
      e += m;
    }
    const float agg = ((s0 + s1) + (s2 + s3)) / fmaxf((float)c, 1.0f);
    const float xv = x[i * H + lane];
    float a0 = 0.f, a1 = 0.f;
#pragma unroll
    for (int k = 0; k < H; k += 2) {
      a0 += bcastf(xv, k)     * wr[k];
      a1 += bcastf(xv, k + 1) * wr[k + 1];
    }
    float acc = agg + bj + a0 + a1;
    if (relu) acc = fmaxf(acc, 0.0f);
    if (out32) out32[i * H + lane] = acc;
    else       out16[i * H + lane] = (_Float16)acc;
  }
}

// out[e] = sum_j relu(P[r,j] + Q[c,j] + db1[j]) * dW2[j] + db2  (P,Q fp16)
// 4-edge unroll: 8 row-gathers in flight per iteration.
__global__ __launch_bounds__(256, 4) void edge_kernel(
    const int* __restrict__ row, const int* __restrict__ col,
    const _Float16* __restrict__ P, const _Float16* __restrict__ Q,
    const float* __restrict__ db1, const float* __restrict__ dW2,
    const float* __restrict__ db2, float* __restrict__ out)
{
  const int lane = threadIdx.x & 63;
  const int gw = (blockIdx.x * 256 + threadIdx.x) >> 6;
  const int nw = (gridDim.x * 256) >> 6;
  const float bj = db1[lane];
  const float w2 = dW2[lane];
  const float b2 = db2[0];
  for (int e = gw * 4; e < NL; e += nw * 4) {
    const int n4 = min(NL - e, 4);
    float h[4];
#pragma unroll
    for (int k = 0; k < 4; k++) {
      if (k < n4) {
        const int r = row[e + k], c = col[e + k];
        const float p = (float)P[(long)r * H + lane];
        const float q = (float)Q[(long)c * H + lane];
        h[k] = fmaxf(p + q + bj, 0.0f) * w2;
      } else h[k] = 0.f;
    }
#pragma unroll
    for (int off = 1; off < 64; off <<= 1) {
#pragma unroll
      for (int k = 0; k < 4; k++) h[k] += __shfl_xor(h[k], off);
    }
    if (lane == 0) {
#pragma unroll
      for (int k = 0; k < 4; k++)
        if (k < n4) out[e + k] = h[k] + b2;
    }
  }
}

extern "C" void kernel_launch(void* const* d_in, const int* in_sizes, int n_in,
                              void* d_out, int out_size, void* d_ws, size_t ws_size,
                              hipStream_t stream) {
  const float* emb_loc = (const float*)d_in[0];
  const float* emb_exp = (const float*)d_in[1];
  const float* W1l_of  = (const float*)d_in[2];
  const float* b1_of   = (const float*)d_in[3];
  const float* W1r_of  = (const float*)d_in[4];
  const float* W1l_rev = (const float*)d_in[5];
  const float* b1_rev  = (const float*)d_in[6];
  const float* W1r_rev = (const float*)d_in[7];
  const float* W2l_of  = (const float*)d_in[8];
  const float* b2_of   = (const float*)d_in[9];
  const float* W2r_of  = (const float*)d_in[10];
  const float* W2l_rev = (const float*)d_in[11];
  const float* b2_rev  = (const float*)d_in[12];
  const float* W2r_rev = (const float*)d_in[13];
  const float* dW1     = (const float*)d_in[14];
  const float* db1     = (const float*)d_in[15];
  const float* dW2     = (const float*)d_in[16];
  const float* db2     = (const float*)d_in[17];
  const int*   edge_of = (const int*)d_in[18];
  const int*   eli     = (const int*)d_in[20];

  const int* src = edge_of;
  const int* dst = edge_of + NE;
  const int* row = eli;
  const int* col = eli + NL;

  if (ws_size < WS_NEED) return;

  char* ws = (char*)d_ws;
  int*            cnt_loc = (int*)(ws);
  int*            cnt_exp = (int*)(ws + 80000);
  int*            nbr_loc = (int*)(ws + 880064);
  unsigned short* nbr_exp = (unsigned short*)(ws + 11120064);
  _Float16*       Ylh     = (_Float16*)(ws + 23920064);
  _Float16*       Y2fh    = (_Float16*)(ws + 26480064);
  float*          z_loc   = (float*)(ws + 29040064);
  _Float16*       PH      = (_Float16*)(ws + 34160064);
  _Float16*       ZE      = (_Float16*)(ws + 39280064);
  _Float16*       TH      = (_Float16*)(ws + 64880064);
  float*          Wf_q    = (float*)(ws + 90480064);
  float*          Wf_y2   = (float*)(ws + 90496448);
  float*          Wf_t2   = (float*)(ws + 90512832);
  float*          Wf_p    = (float*)(ws + 90529216);
  float*          bf_q    = (float*)(ws + 90545600);
  float*          bf_p    = (float*)(ws + 90545856);
  float*          out     = (float*)d_out;

  (void)hipMemsetAsync(ws, 0, 880000, stream);
  fill_kernel<<<NCHUNK * 8, 256, 0, stream>>>(src, dst, cnt_loc, cnt_exp,
                                              nbr_loc, nbr_exp);
  fold_kernel<<<5, 256, 0, stream>>>(W2r_of, W2l_of, W2l_rev, W2r_rev,
                                     dW1, b2_of, b2_rev,
                                     Wf_q, Wf_y2, Wf_t2, Wf_p, bf_q, bf_p);

  // ---- layer 1 ----
  dense_linear_kernel<<<1280, 256, 0, stream>>>(emb_loc, Ylh, W1l_of, NLOC);
  // passA: z_exph = relu(emb_exp@W1r_of + gatherE(Ylh) + b1_of); T1h = emb_exp@W1l_rev
  mfma_pass_kernel<<<NEXP / 16, 256, 0, stream>>>(nbr_exp, cnt_exp, Ylh,
      emb_exp, (const _Float16*)nullptr, ZE, W1r_of, b1_of, 1, TH, W1l_rev);
  loc_gather_kernel<<<1250, 256, 0, stream>>>(nbr_loc, cnt_loc, TH,
      emb_loc, z_loc, (_Float16*)nullptr, W1r_rev, b1_rev, NLOC, 1);

  // ---- layer 2 + decoder transforms (folded: no relu on layer 2) ----
  dense_linear_kernel<<<1280, 256, 0, stream>>>(z_loc, Y2fh, Wf_y2, NLOC);
  // passB: Qh = z_exph@Wf_q + gatherE(Y2fh) + bf_q (in-place over ZE);
  //        T2'h = z_exph@Wf_t2 (over TH; T1h consumed)
  mfma_pass_kernel<<<NEXP / 16, 256, 0, stream>>>(nbr_exp, cnt_exp, Y2fh,
      (const float*)nullptr, ZE, ZE, Wf_q, bf_q, 0, TH, Wf_t2);
  // PH = gatherL(T2'h) + z_loc@Wf_p + bf_p   (decoder-left, folded, fp16 out)
  loc_gather_kernel<<<1250, 256, 0, stream>>>(nbr_loc, cnt_loc, TH,
      z_loc, (float*)nullptr, PH, Wf_p, bf_p, NLOC, 0);

  // ---- decoder edge pass ----
  edge_kernel<<<2048, 256, 0, stream>>>(row, col, PH, ZE,
                                        db1, dW2, db2, out);
}